// Round 1
// baseline (422.577 us; speedup 1.0000x reference)
//
#include <hip/hip_runtime.h>
#include <math.h>

#define B_    256
#define NCH   32
#define T_    2000
#define NTF   4
#define NSF   40
#define NSUB  20
#define TK    25
#define NCLS  4
#define NTAN  210
#define NPAIR 820
#define ACC_STRIDE 860
#define TILE_T 250
#define NTILE  8
#define PL     12

#define ACC_FLOATS (B_*ACC_STRIDE)
#define W2P_OFF ACC_FLOATS                    // 5120 floats: [c][f][s2] as float2 pairs over s
#define W1T_OFF (W2P_OFF + NCH*NTF*NSF)       // 100 floats: [k][f]
#define CB_OFF  (W1T_OFF + NTF*TK)            // 40 floats: effective conv2 bias

#define XS_STR 284        // dwords per c-row of xs[c][i], i in [0,280); b32 reads conflict-free
#define H2_STR 252        // h2[s][t]: 250 data + 2 zero pad
#define LDS_DW 10080      // max(32*284=9088, 40*252=10080)

typedef float v2f __attribute__((ext_vector_type(2)));

__device__ __forceinline__ v2f fma2(v2f a, v2f b, v2f c) {
#if __has_builtin(__builtin_elementwise_fma)
    return __builtin_elementwise_fma(a, b, c);
#else
    v2f r; r.x = fmaf(a.x, b.x, c.x); r.y = fmaf(a.y, b.y, c.y); return r;
#endif
}

__device__ __forceinline__ int pack_ut(int f, int g) {
    return f*NSF - (f*(f-1))/2 + (g - f);
}

// ---------------- K0: weight repack ----------------
// w2p[(c*4+f)*20 + s2] = (w2[2*s2, f, c], w2[2*s2+1, f, c])   (float2)
// w1t[k*4+f]           = w1[f, k]
// cb[s]                = conv2_b[s] + sum_f conv1_b[f] * sum_c w2[s,f,c]
__global__ void prep_kernel(const float* __restrict__ conv1_w,
                            const float* __restrict__ conv1_b,
                            const float* __restrict__ conv2_w,
                            const float* __restrict__ conv2_b,
                            float* __restrict__ ws) {
    int tid = threadIdx.x;
    float* w2p = ws + W2P_OFF;
    float* w1t = ws + W1T_OFF;
    float* cb  = ws + CB_OFF;
    for (int i = tid; i < NCH*NTF*20; i += 256) {
        int s2 = i % 20;
        int cf = i / 20;
        int f  = cf & 3;
        int c  = cf >> 2;
        w2p[2*i]   = conv2_w[((2*s2  )*NTF + f)*NCH + c];
        w2p[2*i+1] = conv2_w[((2*s2+1)*NTF + f)*NCH + c];
    }
    for (int i = tid; i < NTF*TK; i += 256) {
        int f = i & 3;
        int k = i >> 2;
        w1t[i] = conv1_w[f*TK + k];
    }
    if (tid < NSF) {
        float s = conv2_b[tid];
        #pragma unroll
        for (int f = 0; f < NTF; ++f) {
            float a = 0.f;
            for (int c = 0; c < NCH; ++c) a += conv2_w[(tid*NTF + f)*NCH + c];
            s = fmaf(a, conv1_b[f], s);
        }
        cb[tid] = s;
    }
}

// ---------------- K1: fused conv1+conv2+gram, c-outer ----------------
__global__ __launch_bounds__(256, 4)
void conv_gram_kernel(const float* __restrict__ x,
                      const float* __restrict__ wts,
                      float* __restrict__ acc)
{
    __shared__ float lds[LDS_DW];   // union: xs[32][284] then h2[40][252]

    const int tid  = threadIdx.x;
    const int bid  = blockIdx.x;
    const int b    = bid >> 3;
    const int tile = bid & 7;
    const int t0   = tile * TILE_T;

    // ---- stage x c-major: xs[c][i] at lds[c*284+i], i in [0,280) ----
    const float* xb = x + (size_t)b*NCH*T_;
    for (int c = 0; c < NCH; ++c) {
        for (int i = tid; i < 280; i += 256) {
            int tg = t0 + i - PL;
            tg = (tg < 0) ? -tg : tg;
            tg = (tg >= T_) ? (2*T_ - 2 - tg) : tg;
            lds[c*XS_STR + i] = xb[c*T_ + tg];
        }
    }
    __syncthreads();

    const float4* w1t = (const float4*)(wts + W1T_OFF);
    const float2* cbp = (const float2*)(wts + CB_OFF);
    const float2* w2p = (const float2*)(wts + W2P_OFF);

    // ---- fused conv1+conv2: acc2[s2] = (h2[2*s2], h2[2*s2+1]) for t = t0+tid ----
    v2f acc2[20];
    #pragma unroll
    for (int s2 = 0; s2 < 20; ++s2) {
        float2 cbv = cbp[s2];
        v2f a; a.x = cbv.x; a.y = cbv.y;
        acc2[s2] = a;
    }

    #pragma clang loop unroll_count(2)
    for (int c = 0; c < NCH; ++c) {
        const float* xr = &lds[c*XS_STR + tid];
        v2f h1a = (v2f)0.f, h1b = (v2f)0.f;
        #pragma unroll
        for (int k = 0; k < TK; ++k) {
            float xv = xr[k];                 // b32, consecutive lanes: conflict-free
            float4 wq = w1t[k];               // uniform -> scalar load
            v2f w01; w01.x = wq.x; w01.y = wq.y;
            v2f w23; w23.x = wq.z; w23.y = wq.w;
            v2f xv2; xv2.x = xv;  xv2.y = xv;
            h1a = fma2(xv2, w01, h1a);
            h1b = fma2(xv2, w23, h1b);
        }
        const float2* wp = w2p + c*(NTF*20);
        float hf[4] = {h1a.x, h1a.y, h1b.x, h1b.y};
        #pragma unroll
        for (int f = 0; f < NTF; ++f) {
            v2f hb; hb.x = hf[f]; hb.y = hf[f];
            #pragma unroll
            for (int s2 = 0; s2 < 20; ++s2) {
                float2 w = wp[f*20 + s2];     // uniform -> scalar load
                v2f wv; wv.x = w.x; wv.y = w.y;
                acc2[s2] = fma2(hb, wv, acc2[s2]);
            }
        }
    }
    __syncthreads();   // xs dead; lds becomes h2

    // ---- write h2[s][t] rows from registers ----
    if (tid < H2_STR) {
        const bool valid = (tid < TILE_T);
        #pragma unroll
        for (int s2 = 0; s2 < 20; ++s2) {
            lds[(2*s2  )*H2_STR + tid] = valid ? acc2[s2].x : 0.f;
            lds[(2*s2+1)*H2_STR + tid] = valid ? acc2[s2].y : 0.f;
        }
    }
    __syncthreads();

    float* accb = acc + b*ACC_STRIDE;

    // ---- gram: 4x4 row-block tiles, 55 threads (wave 0) ----
    if (tid < 55) {
        int bf = 0, rem = tid;
        while (rem >= 10 - bf) { rem -= 10 - bf; bf++; }
        int bg = bf + rem;

        const float4* rA[4];
        const float4* rB[4];
        #pragma unroll
        for (int a = 0; a < 4; ++a) {
            rA[a] = (const float4*)&lds[(4*bf + a)*H2_STR];
            rB[a] = (const float4*)&lds[(4*bg + a)*H2_STR];
        }
        v2f accL[16], accH[16];
        #pragma unroll
        for (int i = 0; i < 16; ++i) { accL[i] = (v2f)0.f; accH[i] = (v2f)0.f; }

        #pragma unroll 7
        for (int q = 0; q < H2_STR/4; ++q) {
            float4 av[4], bv[4];
            #pragma unroll
            for (int a = 0; a < 4; ++a) av[a] = rA[a][q];
            #pragma unroll
            for (int a = 0; a < 4; ++a) bv[a] = rB[a][q];
            #pragma unroll
            for (int a = 0; a < 4; ++a) {
                v2f aL; aL.x = av[a].x; aL.y = av[a].y;
                v2f aH; aH.x = av[a].z; aH.y = av[a].w;
                #pragma unroll
                for (int g = 0; g < 4; ++g) {
                    v2f bL; bL.x = bv[g].x; bL.y = bv[g].y;
                    v2f bH; bH.x = bv[g].z; bH.y = bv[g].w;
                    accL[a*4+g] = fma2(aL, bL, accL[a*4+g]);
                    accH[a*4+g] = fma2(aH, bH, accH[a*4+g]);
                }
            }
        }
        #pragma unroll
        for (int a = 0; a < 4; ++a) {
            #pragma unroll
            for (int g = 0; g < 4; ++g) {
                int f  = 4*bf + a;
                int gg = 4*bg + g;
                if (f <= gg) {
                    v2f sL = accL[a*4+g], sH = accH[a*4+g];
                    float s = (sL.x + sL.y) + (sH.x + sH.y);
                    atomicAdd(&accb[pack_ut(f, gg)], s);
                }
            }
        }
    }

    // ---- column sums: wave 1 ----
    if (tid >= 64 && tid < 64 + NSF) {
        int row = tid - 64;
        const float4* rr = (const float4*)&lds[row*H2_STR];
        float csum = 0.f;
        #pragma unroll 7
        for (int q = 0; q < H2_STR/4; ++q) {
            float4 v = rr[q];
            csum += (v.x + v.y) + (v.z + v.w);
        }
        atomicAdd(&accb[NPAIR + row], csum);
    }
}

// ---------------- K2: cov -> bimap -> fused 2x2-block Jacobi -> log -> head ----------------
__device__ __forceinline__ void pq_sched(int r, int k, int& p, int& q) {
    if (k == 0) { p = 19; q = r; }
    else {
        int a = r + k;      if (a >= 19) a -= 19;
        int d = r - k + 19; if (d >= 19) d -= 19;
        p = a; q = d;
    }
}

__global__ __launch_bounds__(128)
void finalize_kernel(const float* __restrict__ acc,
                     const float* __restrict__ W_bimap,
                     const float* __restrict__ clf_w,
                     const float* __restrict__ clf_b,
                     float* __restrict__ out)
{
    __shared__ float C[NSF*NSF];
    __shared__ float Wb[NSUB*NSF];
    __shared__ float M[NSUB*NSF];
    __shared__ float A[NSUB*21];
    __shared__ float V[NSUB*21];
    __shared__ float cs_c[10], cs_s[10];
    __shared__ float lam[NSUB];
    __shared__ float z[NTAN];

    const int tid = threadIdx.x;
    const int b   = blockIdx.x;
    const float* accb = acc + b*ACC_STRIDE;

    for (int i = tid; i < NSF*NSF; i += 128) {
        int f = i / NSF, g = i % NSF;
        int lo = f < g ? f : g;
        int hi = f < g ? g : f;
        double G  = (double)accb[pack_ut(lo, hi)];
        double sf = (double)accb[NPAIR + f];
        double sg = (double)accb[NPAIR + g];
        C[i] = (float)((G - sf*sg/(double)T_) / (double)(T_ - 1));
    }
    for (int i = tid; i < NSUB*NSF; i += 128) Wb[i] = W_bimap[i];
    __syncthreads();

    for (int i = tid; i < NSUB*NSF; i += 128) {
        int r = i / NSF, g = i % NSF;
        float s = 0.f;
        #pragma unroll 8
        for (int f = 0; f < NSF; ++f) s = fmaf(Wb[r*NSF+f], C[f*NSF+g], s);
        M[i] = s;
    }
    __syncthreads();

    for (int i = tid; i < NSUB*NSUB; i += 128) {
        int r = i / NSUB, j = i % NSUB;
        float s = 0.f;
        #pragma unroll 8
        for (int g = 0; g < NSF; ++g) s = fmaf(M[r*NSF+g], Wb[j*NSF+g], s);
        A[r*21+j] = s;
        V[r*21+j] = (r == j) ? 1.f : 0.f;
    }
    __syncthreads();

    const int kk = tid / 10;
    const int ll = tid - 10*(tid/10);

    for (int sweep = 0; sweep < 7; ++sweep) {
        for (int r = 0; r < 19; ++r) {
            if (tid < 10) {
                int p, q; pq_sched(r, tid, p, q);
                float app = A[p*21+p], aqq = A[q*21+q], apq = A[p*21+q];
                float c = 1.f, s = 0.f;
                if (fabsf(apq) > 1e-30f) {
                    float tau = (aqq - app) / (2.f*apq);
                    float t = 1.f / (fabsf(tau) + sqrtf(1.f + tau*tau));
                    if (tau < 0.f) t = -t;
                    c = 1.f / sqrtf(1.f + t*t);
                    s = t * c;
                }
                cs_c[tid] = c; cs_s[tid] = s;
            }
            __syncthreads();
            if (tid < 100) {
                int pk, qk, pl, ql;
                pq_sched(r, kk, pk, qk);
                pq_sched(r, ll, pl, ql);
                float ck = cs_c[kk], sk = cs_s[kk];
                float cl = cs_c[ll], sl = cs_s[ll];
                float a00 = A[pk*21+pl], a01 = A[pk*21+ql];
                float a10 = A[qk*21+pl], a11 = A[qk*21+ql];
                float t00 = ck*a00 - sk*a10, t01 = ck*a01 - sk*a11;
                float t10 = sk*a00 + ck*a10, t11 = sk*a01 + ck*a11;
                A[pk*21+pl] = cl*t00 - sl*t01;
                A[pk*21+ql] = sl*t00 + cl*t01;
                A[qk*21+pl] = cl*t10 - sl*t11;
                A[qk*21+ql] = sl*t10 + cl*t11;
                float v00 = V[pk*21+pl], v01 = V[pk*21+ql];
                float v10 = V[qk*21+pl], v11 = V[qk*21+ql];
                V[pk*21+pl] = cl*v00 - sl*v01;
                V[pk*21+ql] = sl*v00 + cl*v01;
                V[qk*21+pl] = cl*v10 - sl*v11;
                V[qk*21+ql] = sl*v10 + cl*v11;
            }
            __syncthreads();
        }
    }

    if (tid < NSUB) {
        float w = A[tid*21+tid];
        lam[tid] = logf(fmaxf(w, 1e-4f));
    }
    __syncthreads();

    for (int p = tid; p < NTAN; p += 128) {
        int i = 0, rem = p;
        while (rem >= NSUB - i) { rem -= NSUB - i; i++; }
        int j = i + rem;
        float s = 0.f;
        #pragma unroll 5
        for (int k = 0; k < NSUB; ++k) s = fmaf(V[i*21+k]*lam[k], V[j*21+k], s);
        z[p] = (i == j) ? s : s * 1.41421356237309515f;
    }
    __syncthreads();

    if (tid < NCLS) {
        float s = clf_b[tid];
        for (int p = 0; p < NTAN; ++p) s = fmaf(clf_w[tid*NTAN+p], z[p], s);
        out[b*NCLS + tid] = s;
    }
}

// ---------------- launch ----------------
extern "C" void kernel_launch(void* const* d_in, const int* in_sizes, int n_in,
                              void* d_out, int out_size, void* d_ws, size_t ws_size,
                              hipStream_t stream) {
    const float* x       = (const float*)d_in[0];
    const float* conv1_w = (const float*)d_in[1];
    const float* conv1_b = (const float*)d_in[2];
    const float* conv2_w = (const float*)d_in[3];
    const float* conv2_b = (const float*)d_in[4];
    const float* W_bimap = (const float*)d_in[5];
    const float* clf_w   = (const float*)d_in[6];
    const float* clf_b   = (const float*)d_in[7];
    float* out = (float*)d_out;
    float* ws  = (float*)d_ws;

    hipMemsetAsync(ws, 0, (size_t)ACC_FLOATS*sizeof(float), stream);

    prep_kernel<<<1, 256, 0, stream>>>(conv1_w, conv1_b, conv2_w, conv2_b, ws);
    conv_gram_kernel<<<B_*NTILE, 256, 0, stream>>>(x, ws, ws);
    finalize_kernel<<<B_, 128, 0, stream>>>(ws, W_bimap, clf_w, clf_b, out);
}

// Round 2
// 336.180 us; speedup vs baseline: 1.2570x; 1.2570x over previous
//
#include <hip/hip_runtime.h>
#include <math.h>

#define B_    256
#define NCH   32
#define T_    2000
#define NTF   4
#define NSF   40
#define NSUB  20
#define TK    25
#define NCLS  4
#define NTAN  210
#define NPAIR 820
#define ACC_STRIDE 860
#define TILE_T 250
#define NTILE  8
#define PL     12

#define ACC_FLOATS (B_*ACC_STRIDE)
#define W2Q_OFF ACC_FLOATS                    // 5120 floats: [c][f][s4] float4 over s
#define W1T_OFF (W2Q_OFF + NSF*NTF*NCH)       // 100 floats:  [k][f]
#define CB_OFF  (W1T_OFF + NTF*TK)            // 40 floats: effective conv2 bias

#define XS_TSTR 36         // dwords per t-row of xs[t][c]; 16B-aligned, 2-way banks (free)
#define H2_STR  252        // h2[s][t]: 250 data + 2 zero pad
#define LDS_DW  10080      // max(280*36, 40*252) = 10080 dwords = 40320 B

typedef float v2f __attribute__((ext_vector_type(2)));
typedef float v4f __attribute__((ext_vector_type(4)));

__device__ __forceinline__ v2f fma2(v2f a, v2f b, v2f c) {
#if __has_builtin(__builtin_elementwise_fma)
    return __builtin_elementwise_fma(a, b, c);
#else
    v2f r; r.x = fmaf(a.x, b.x, c.x); r.y = fmaf(a.y, b.y, c.y); return r;
#endif
}

__device__ __forceinline__ v4f fma4(v4f a, v4f b, v4f c) {
#if __has_builtin(__builtin_elementwise_fma)
    return __builtin_elementwise_fma(a, b, c);
#else
    v4f r;
    r.x = fmaf(a.x, b.x, c.x); r.y = fmaf(a.y, b.y, c.y);
    r.z = fmaf(a.z, b.z, c.z); r.w = fmaf(a.w, b.w, c.w);
    return r;
#endif
}

__device__ __forceinline__ int pack_ut(int f, int g) {
    return f*NSF - (f*(f-1))/2 + (g - f);
}

// ---------------- K0: weight repack ----------------
// w2q[((c*4+f)*10 + s4)*4 + j] = conv2_w[s=4*s4+j][f][c]
// w1t[k*4+f]                   = conv1_w[f][k]
// cb[s] = conv2_b[s] + sum_f conv1_b[f] * sum_c conv2_w[s][f][c]
__global__ void prep_kernel(const float* __restrict__ conv1_w,
                            const float* __restrict__ conv1_b,
                            const float* __restrict__ conv2_w,
                            const float* __restrict__ conv2_b,
                            float* __restrict__ ws) {
    int tid = threadIdx.x;
    float* w2q = ws + W2Q_OFF;
    float* w1t = ws + W1T_OFF;
    float* cb  = ws + CB_OFF;
    for (int i = tid; i < NSF*NTF*NCH; i += 256) {
        int j  = i & 3;
        int q  = i >> 2;
        int s4 = q % 10;
        int cf = q / 10;
        int f  = cf & 3;
        int c  = cf >> 2;
        int s  = 4*s4 + j;
        w2q[i] = conv2_w[(s*NTF + f)*NCH + c];
    }
    for (int i = tid; i < NTF*TK; i += 256) {
        int f = i & 3;
        int k = i >> 2;
        w1t[i] = conv1_w[f*TK + k];
    }
    if (tid < NSF) {
        float s = conv2_b[tid];
        #pragma unroll
        for (int f = 0; f < NTF; ++f) {
            float a = 0.f;
            for (int c = 0; c < NCH; ++c) a += conv2_w[(tid*NTF + f)*NCH + c];
            s = fmaf(a, conv1_b[f], s);
        }
        cb[tid] = s;
    }
}

// ---------------- K1: fused conv1+conv2+gram, channel-chunked ----------------
__global__ __launch_bounds__(256, 3)
void conv_gram_kernel(const float* __restrict__ x,
                      const float* __restrict__ wts,
                      float* __restrict__ acc)
{
    __shared__ float lds[LDS_DW];   // union: xs[280][36] then h2[40][252]

    const int tid  = threadIdx.x;
    const int bid  = blockIdx.x;
    const int b    = bid >> 3;
    const int tile = bid & 7;
    const int t0   = tile * TILE_T;

    // ---- stage x transposed: xs[i][c] at lds[i*36+c], i in [0,280) ----
    const float* xb = x + (size_t)b*NCH*T_;
    for (int li = tid; li < NCH*280; li += 256) {
        int c = li / 280;
        int i = li - c*280;
        int tg = t0 + i - PL;
        tg = (tg < 0) ? -tg : tg;
        tg = (tg >= T_) ? (2*T_ - 2 - tg) : tg;
        lds[i*XS_TSTR + c] = xb[c*T_ + tg];
    }
    __syncthreads();

    const float4* w1t = (const float4*)(wts + W1T_OFF);
    const float4* w2q = (const float4*)(wts + W2Q_OFF);
    const float4* cb4 = (const float4*)(wts + CB_OFF);

    // ---- persistent accumulator: acc4[s4] = h2[4*s4 .. 4*s4+3] at t = t0+tid ----
    v4f acc4[10];
    #pragma unroll
    for (int s4 = 0; s4 < 10; ++s4) {
        float4 t = cb4[s4];
        v4f a; a.x = t.x; a.y = t.y; a.z = t.z; a.w = t.w;
        acc4[s4] = a;
    }

    // ---- 4 chunks of 8 channels: conv1 into h1[16] v2f, fold into acc4 ----
    #pragma clang loop unroll(disable)
    for (int ch = 0; ch < 4; ++ch) {
        v2f h1[16];
        #pragma unroll
        for (int i = 0; i < 16; ++i) h1[i] = (v2f)0.f;

        #pragma clang loop unroll(disable)
        for (int k = 0; k < TK; ++k) {
            float4 wq = w1t[k];
            v2f w01; w01.x = wq.x; w01.y = wq.y;
            v2f w23; w23.x = wq.z; w23.y = wq.w;
            const float4* xr = (const float4*)&lds[(tid + k)*XS_TSTR + 8*ch];
            float4 xa = xr[0];
            float4 xb4 = xr[1];
            float xv[8] = {xa.x, xa.y, xa.z, xa.w, xb4.x, xb4.y, xb4.z, xb4.w};
            #pragma unroll
            for (int c = 0; c < 8; ++c) {
                v2f xc; xc.x = xv[c]; xc.y = xv[c];
                h1[2*c]   = fma2(xc, w01, h1[2*c]);
                h1[2*c+1] = fma2(xc, w23, h1[2*c+1]);
            }
        }

        const float4* wp = w2q + (ch*8)*(NTF*10);
        #pragma unroll
        for (int c = 0; c < 8; ++c) {
            float hf[4] = {h1[2*c].x, h1[2*c].y, h1[2*c+1].x, h1[2*c+1].y};
            #pragma unroll
            for (int f = 0; f < 4; ++f) {
                v4f hb; hb.x = hf[f]; hb.y = hf[f]; hb.z = hf[f]; hb.w = hf[f];
                #pragma unroll
                for (int s4 = 0; s4 < 10; ++s4) {
                    float4 w = wp[(c*4 + f)*10 + s4];
                    v4f wv; wv.x = w.x; wv.y = w.y; wv.z = w.z; wv.w = w.w;
                    acc4[s4] = fma4(hb, wv, acc4[s4]);
                }
            }
        }
    }
    __syncthreads();   // xs dead; lds becomes h2

    // ---- write h2[s][t] rows from registers ----
    if (tid < H2_STR) {
        const bool valid = (tid < TILE_T);
        #pragma unroll
        for (int s4 = 0; s4 < 10; ++s4) {
            v4f a = acc4[s4];
            lds[(4*s4+0)*H2_STR + tid] = valid ? a.x : 0.f;
            lds[(4*s4+1)*H2_STR + tid] = valid ? a.y : 0.f;
            lds[(4*s4+2)*H2_STR + tid] = valid ? a.z : 0.f;
            lds[(4*s4+3)*H2_STR + tid] = valid ? a.w : 0.f;
        }
    }
    __syncthreads();

    float* accb = acc + b*ACC_STRIDE;

    // ---- gram: 4x4 row-block tiles, 55 threads (wave 0) ----
    if (tid < 55) {
        int bf = 0, rem = tid;
        while (rem >= 10 - bf) { rem -= 10 - bf; bf++; }
        int bg = bf + rem;

        const float4* rA[4];
        const float4* rB[4];
        #pragma unroll
        for (int a = 0; a < 4; ++a) {
            rA[a] = (const float4*)&lds[(4*bf + a)*H2_STR];
            rB[a] = (const float4*)&lds[(4*bg + a)*H2_STR];
        }
        v2f accL[16], accH[16];
        #pragma unroll
        for (int i = 0; i < 16; ++i) { accL[i] = (v2f)0.f; accH[i] = (v2f)0.f; }

        #pragma unroll 7
        for (int q = 0; q < H2_STR/4; ++q) {
            float4 av[4], bv[4];
            #pragma unroll
            for (int a = 0; a < 4; ++a) av[a] = rA[a][q];
            #pragma unroll
            for (int a = 0; a < 4; ++a) bv[a] = rB[a][q];
            #pragma unroll
            for (int a = 0; a < 4; ++a) {
                v2f aL; aL.x = av[a].x; aL.y = av[a].y;
                v2f aH; aH.x = av[a].z; aH.y = av[a].w;
                #pragma unroll
                for (int g = 0; g < 4; ++g) {
                    v2f bL; bL.x = bv[g].x; bL.y = bv[g].y;
                    v2f bH; bH.x = bv[g].z; bH.y = bv[g].w;
                    accL[a*4+g] = fma2(aL, bL, accL[a*4+g]);
                    accH[a*4+g] = fma2(aH, bH, accH[a*4+g]);
                }
            }
        }
        #pragma unroll
        for (int a = 0; a < 4; ++a) {
            #pragma unroll
            for (int g = 0; g < 4; ++g) {
                int f  = 4*bf + a;
                int gg = 4*bg + g;
                if (f <= gg) {
                    v2f sL = accL[a*4+g], sH = accH[a*4+g];
                    float s = (sL.x + sL.y) + (sH.x + sH.y);
                    atomicAdd(&accb[pack_ut(f, gg)], s);
                }
            }
        }
    }

    // ---- column sums: wave 1 ----
    if (tid >= 64 && tid < 64 + NSF) {
        int row = tid - 64;
        const float4* rr = (const float4*)&lds[row*H2_STR];
        float csum = 0.f;
        #pragma unroll 7
        for (int q = 0; q < H2_STR/4; ++q) {
            float4 v = rr[q];
            csum += (v.x + v.y) + (v.z + v.w);
        }
        atomicAdd(&accb[NPAIR + row], csum);
    }
}

// ---------------- K2: cov -> bimap -> fused 2x2-block Jacobi -> log -> head ----------------
__device__ __forceinline__ void pq_sched(int r, int k, int& p, int& q) {
    if (k == 0) { p = 19; q = r; }
    else {
        int a = r + k;      if (a >= 19) a -= 19;
        int d = r - k + 19; if (d >= 19) d -= 19;
        p = a; q = d;
    }
}

__global__ __launch_bounds__(128)
void finalize_kernel(const float* __restrict__ acc,
                     const float* __restrict__ W_bimap,
                     const float* __restrict__ clf_w,
                     const float* __restrict__ clf_b,
                     float* __restrict__ out)
{
    __shared__ float C[NSF*NSF];
    __shared__ float Wb[NSUB*NSF];
    __shared__ float M[NSUB*NSF];
    __shared__ float A[NSUB*21];
    __shared__ float V[NSUB*21];
    __shared__ float cs_c[10], cs_s[10];
    __shared__ float lam[NSUB];
    __shared__ float z[NTAN];

    const int tid = threadIdx.x;
    const int b   = blockIdx.x;
    const float* accb = acc + b*ACC_STRIDE;

    for (int i = tid; i < NSF*NSF; i += 128) {
        int f = i / NSF, g = i % NSF;
        int lo = f < g ? f : g;
        int hi = f < g ? g : f;
        double G  = (double)accb[pack_ut(lo, hi)];
        double sf = (double)accb[NPAIR + f];
        double sg = (double)accb[NPAIR + g];
        C[i] = (float)((G - sf*sg/(double)T_) / (double)(T_ - 1));
    }
    for (int i = tid; i < NSUB*NSF; i += 128) Wb[i] = W_bimap[i];
    __syncthreads();

    for (int i = tid; i < NSUB*NSF; i += 128) {
        int r = i / NSF, g = i % NSF;
        float s = 0.f;
        #pragma unroll 8
        for (int f = 0; f < NSF; ++f) s = fmaf(Wb[r*NSF+f], C[f*NSF+g], s);
        M[i] = s;
    }
    __syncthreads();

    for (int i = tid; i < NSUB*NSUB; i += 128) {
        int r = i / NSUB, j = i % NSUB;
        float s = 0.f;
        #pragma unroll 8
        for (int g = 0; g < NSF; ++g) s = fmaf(M[r*NSF+g], Wb[j*NSF+g], s);
        A[r*21+j] = s;
        V[r*21+j] = (r == j) ? 1.f : 0.f;
    }
    __syncthreads();

    const int kk = tid / 10;
    const int ll = tid - 10*(tid/10);

    for (int sweep = 0; sweep < 7; ++sweep) {
        for (int r = 0; r < 19; ++r) {
            if (tid < 10) {
                int p, q; pq_sched(r, tid, p, q);
                float app = A[p*21+p], aqq = A[q*21+q], apq = A[p*21+q];
                float c = 1.f, s = 0.f;
                if (fabsf(apq) > 1e-30f) {
                    float tau = (aqq - app) / (2.f*apq);
                    float t = 1.f / (fabsf(tau) + sqrtf(1.f + tau*tau));
                    if (tau < 0.f) t = -t;
                    c = 1.f / sqrtf(1.f + t*t);
                    s = t * c;
                }
                cs_c[tid] = c; cs_s[tid] = s;
            }
            __syncthreads();
            if (tid < 100) {
                int pk, qk, pl, ql;
                pq_sched(r, kk, pk, qk);
                pq_sched(r, ll, pl, ql);
                float ck = cs_c[kk], sk = cs_s[kk];
                float cl = cs_c[ll], sl = cs_s[ll];
                float a00 = A[pk*21+pl], a01 = A[pk*21+ql];
                float a10 = A[qk*21+pl], a11 = A[qk*21+ql];
                float t00 = ck*a00 - sk*a10, t01 = ck*a01 - sk*a11;
                float t10 = sk*a00 + ck*a10, t11 = sk*a01 + ck*a11;
                A[pk*21+pl] = cl*t00 - sl*t01;
                A[pk*21+ql] = sl*t00 + cl*t01;
                A[qk*21+pl] = cl*t10 - sl*t11;
                A[qk*21+ql] = sl*t10 + cl*t11;
                float v00 = V[pk*21+pl], v01 = V[pk*21+ql];
                float v10 = V[qk*21+pl], v11 = V[qk*21+ql];
                V[pk*21+pl] = cl*v00 - sl*v01;
                V[pk*21+ql] = sl*v00 + cl*v01;
                V[qk*21+pl] = cl*v10 - sl*v11;
                V[qk*21+ql] = sl*v10 + cl*v11;
            }
            __syncthreads();
        }
    }

    if (tid < NSUB) {
        float w = A[tid*21+tid];
        lam[tid] = logf(fmaxf(w, 1e-4f));
    }
    __syncthreads();

    for (int p = tid; p < NTAN; p += 128) {
        int i = 0, rem = p;
        while (rem >= NSUB - i) { rem -= NSUB - i; i++; }
        int j = i + rem;
        float s = 0.f;
        #pragma unroll 5
        for (int k = 0; k < NSUB; ++k) s = fmaf(V[i*21+k]*lam[k], V[j*21+k], s);
        z[p] = (i == j) ? s : s * 1.41421356237309515f;
    }
    __syncthreads();

    if (tid < NCLS) {
        float s = clf_b[tid];
        for (int p = 0; p < NTAN; ++p) s = fmaf(clf_w[tid*NTAN+p], z[p], s);
        out[b*NCLS + tid] = s;
    }
}

// ---------------- launch ----------------
extern "C" void kernel_launch(void* const* d_in, const int* in_sizes, int n_in,
                              void* d_out, int out_size, void* d_ws, size_t ws_size,
                              hipStream_t stream) {
    const float* x       = (const float*)d_in[0];
    const float* conv1_w = (const float*)d_in[1];
    const float* conv1_b = (const float*)d_in[2];
    const float* conv2_w = (const float*)d_in[3];
    const float* conv2_b = (const float*)d_in[4];
    const float* W_bimap = (const float*)d_in[5];
    const float* clf_w   = (const float*)d_in[6];
    const float* clf_b   = (const float*)d_in[7];
    float* out = (float*)d_out;
    float* ws  = (float*)d_ws;

    hipMemsetAsync(ws, 0, (size_t)ACC_FLOATS*sizeof(float), stream);

    prep_kernel<<<1, 256, 0, stream>>>(conv1_w, conv1_b, conv2_w, conv2_b, ws);
    conv_gram_kernel<<<B_*NTILE, 256, 0, stream>>>(x, ws, ws);
    finalize_kernel<<<B_, 128, 0, stream>>>(ws, W_bimap, clf_w, clf_b, out);
}